// Round 13
// baseline (838.939 us; speedup 1.0000x reference)
//
#include <hip/hip_runtime.h>
#include <hip/hip_bf16.h>

typedef __hip_bfloat16 hbf16;
typedef unsigned short u16;
typedef __bf16 bf16x8 __attribute__((ext_vector_type(8)));
typedef float f32x4 __attribute__((ext_vector_type(4)));

#define N_USERS 80000
#define N_ITEMS 20000
#define NTOT    100000
#define NEDGE   1600000
#define DDIM    128
#define NLAY    3
#define KHOP    3
#define NB      4096
#define LBM     128    // rows per layer block
#define NBUK    98     // ceil(NTOT / 1024) row-buckets
#define BROWS   1024   // rows per bucket
#define BSH     10     // log2(BROWS)

__device__ inline u16 f2bfu(float f) { __bf16 h = (__bf16)f; return __builtin_bit_cast(u16, h); }
__device__ inline float bfu2f(u16 u) { return __builtin_bit_cast(float, (unsigned)u << 16); }

__global__ void build_ego_kernel(const float* __restrict__ feat, const float* __restrict__ user_emb,
                                 const float* __restrict__ item_emb1, const float* __restrict__ item_emb2,
                                 u16* __restrict__ ego, int* __restrict__ bbins,
                                 unsigned char* __restrict__ flags) {
    if (blockIdx.x == 0 && threadIdx.x < NBUK) bbins[threadIdx.x] = 0;
    int i = blockIdx.x * 256 + threadIdx.x;   // exactly NTOT*DDIM threads
    int n = i >> 7, d = i & 127;
    if (d == 0) flags[n] = 0;
    float v;
    if (n < N_USERS) {
        v = (d < 64) ? user_emb[n*64 + d] : feat[n*64 + d - 64];
    } else {
        int m = n - N_USERS;
        v = (d < 64) ? item_emb1[m*64 + d] : item_emb2[m*64 + d - 64];
    }
    ego[i] = f2bfu(v);
}

// transpose 6 128x128 fp32 matrices into bf16 (WT[n][k] = W[k][n])
__global__ void transpose_w_kernel(const float* __restrict__ Wgc, const float* __restrict__ Wbi,
                                   u16* __restrict__ WTgc, u16* __restrict__ WTbi) {
    __shared__ float t[32][33];
    int z = blockIdx.z;
    const float* W = (z < 3) ? (Wgc + (size_t)z * 16384) : (Wbi + (size_t)(z - 3) * 16384);
    u16* WT = (z < 3) ? (WTgc + (size_t)z * 16384) : (WTbi + (size_t)(z - 3) * 16384);
    int r0 = blockIdx.y * 32, c0 = blockIdx.x * 32;
    for (int i = threadIdx.y; i < 32; i += 8)
        t[i][threadIdx.x] = W[(size_t)(r0 + i) * 128 + c0 + threadIdx.x];
    __syncthreads();
    for (int i = threadIdx.y; i < 32; i += 8)
        WT[(size_t)(c0 + i) * 128 + r0 + threadIdx.x] = f2bfu(t[threadIdx.x][i]);
}

// Pass A: bucket histogram (98 bins, LDS-aggregated)
__global__ __launch_bounds__(256) void bhist_kernel(const int* __restrict__ er,
                                                    int* __restrict__ bbins) {
    __shared__ int l[NBUK];
    int tid = threadIdx.x;
    if (tid < NBUK) l[tid] = 0;
    __syncthreads();
    for (int i = blockIdx.x * 256 + tid; i < NEDGE; i += gridDim.x * 256)
        atomicAdd(&l[er[i] >> BSH], 1);
    __syncthreads();
    if (tid < NBUK && l[tid]) atomicAdd(&bbins[tid], l[tid]);
}

// Pass B: beta softmax + bucket exclusive scan (merged tiny scalar kernels)
__global__ void beta_bscan_kernel(const float* __restrict__ alphas, float* __restrict__ beta,
                                  const int* __restrict__ bbins, int* __restrict__ bbase,
                                  int* __restrict__ bcur) {
    if (threadIdx.x == 0 && blockIdx.x == 0) {
        for (int k = 0; k < NLAY; ++k) {
            float a[KHOP];
            float m = -1e30f;
            for (int i = 0; i < KHOP; ++i) { a[i] = alphas[k*KHOP+i]; m = fmaxf(m, a[i]); }
            float s = 0.f;
            for (int i = 0; i < KHOP; ++i) { a[i] = expf(a[i] - m); s += a[i]; }
            for (int i = 0; i < KHOP; ++i) beta[k*KHOP+i] = a[i] / s;
        }
        int acc = 0;
        for (int b = 0; b < NBUK; ++b) { int t = bbins[b]; bbase[b] = acc; bcur[b] = acc; acc += t; }
        bbase[NBUK] = acc;
    }
}

// Pass C: append edges into row-buckets (per-block LDS aggregation -> contiguous runs)
__global__ __launch_bounds__(256) void bappend_kernel(
    const int* __restrict__ er, const int* __restrict__ ec, const float* __restrict__ ev,
    int* __restrict__ bcur, int* __restrict__ tmprow, int2* __restrict__ tmpcv) {
    __shared__ int lcnt[NBUK], lbase[NBUK], lrank[NBUK];
    int tid = threadIdx.x;
    for (int b = tid; b < NBUK; b += 256) { lcnt[b] = 0; lrank[b] = 0; }
    __syncthreads();
    int base = blockIdx.x * 2048;
    int r[8], c[8], vb[8], bk[8];
    bool ok[8];
    #pragma unroll
    for (int k = 0; k < 8; ++k) {
        int i = base + k * 256 + tid;
        ok[k] = i < NEDGE;
        bk[k] = 0;
        if (ok[k]) {
            r[k] = er[i]; c[k] = ec[i]; vb[k] = __float_as_int(ev[i]);
            bk[k] = r[k] >> BSH;
            atomicAdd(&lcnt[bk[k]], 1);
        }
    }
    __syncthreads();
    for (int b = tid; b < NBUK; b += 256)
        lbase[b] = lcnt[b] ? atomicAdd(&bcur[b], lcnt[b]) : 0;
    __syncthreads();
    #pragma unroll
    for (int k = 0; k < 8; ++k) {
        if (ok[k]) {
            int rank = atomicAdd(&lrank[bk[k]], 1);
            int pos = lbase[bk[k]] + rank;
            tmprow[pos] = r[k];
            tmpcv[pos] = make_int2(c[k], vb[k]);
        }
    }
}

// Pass D: one block per bucket (98 blocks). LDS row-histogram + 1024-wide scan ->
// rowptr (coalesced), then LDS running counters place edges (6B records: col + bf16 val).
__global__ __launch_bounds__(1024) void bfinal_kernel(
    const int* __restrict__ bbase, const int* __restrict__ tmprow,
    const int2* __restrict__ tmpcv, int* __restrict__ rowptr,
    int* __restrict__ ecol, u16* __restrict__ eval) {
    __shared__ int lhist[BROWS];
    __shared__ int s2[1024];
    int b = blockIdx.x, tid = threadIdx.x;
    int s = bbase[b], e = bbase[b + 1];
    int rbase = b << BSH;
    int nrows = min(NTOT - rbase, BROWS);
    lhist[tid] = 0;
    __syncthreads();
    for (int i = s + tid; i < e; i += 1024)
        atomicAdd(&lhist[tmprow[i] - rbase], 1);
    __syncthreads();
    int a = lhist[tid];
    s2[tid] = a;
    __syncthreads();
    for (int off = 1; off < 1024; off <<= 1) {
        int t = (tid >= off) ? s2[tid - off] : 0;
        __syncthreads();
        s2[tid] += t;
        __syncthreads();
    }
    int excl = s2[tid] - a;
    if (tid < nrows) rowptr[rbase + tid] = s + excl;
    if (b == NBUK - 1 && tid == 0) rowptr[NTOT] = NEDGE;
    lhist[tid] = excl;
    __syncthreads();
    for (int i = s + tid; i < e; i += 1024) {
        int2 rec = tmpcv[i];
        int lr = tmprow[i] - rbase;
        int p = atomicAdd(&lhist[lr], 1);
        ecol[s + p] = rec.x;
        eval[s + p] = f2bfu(__int_as_float(rec.y));
    }
}

// 16 lanes per row, 16 rows per 256-thread block; each lane owns 8 columns (16B loads).
// 6-byte edge records (col int + bf16 val, both nontemporal). At the random-gather
// BW floor (r11/r12 analysis); edge-stream bytes are the only remaining knob.
__global__ __launch_bounds__(256) void spmm_kernel(
    const int* __restrict__ rowptr, const int* __restrict__ ecol,
    const u16* __restrict__ eval,
    const u16* __restrict__ X, u16* __restrict__ Y) {
    int tid = threadIdx.x;
    int r = blockIdx.x * 16 + (tid >> 4);
    int lane = tid & 15;
    int s = rowptr[r], e = rowptr[r + 1];
    float acc[8];
    #pragma unroll
    for (int i = 0; i < 8; ++i) acc[i] = 0.f;
    const u16* xb = X + lane * 8;
    int j = s;
    for (; j + 8 <= e; j += 8) {
        int cc[8]; float vv[8];
        #pragma unroll
        for (int u = 0; u < 8; ++u) cc[u] = __builtin_nontemporal_load(ecol + j + u);
        #pragma unroll
        for (int u = 0; u < 8; ++u) vv[u] = bfu2f(__builtin_nontemporal_load(eval + j + u));
        bf16x8 x[8];
        #pragma unroll
        for (int u = 0; u < 8; ++u)
            x[u] = *reinterpret_cast<const bf16x8*>(xb + (size_t)cc[u] * DDIM);
        __builtin_amdgcn_sched_barrier(0);
        #pragma unroll
        for (int u = 0; u < 8; ++u) {
            #pragma unroll
            for (int i = 0; i < 8; ++i) acc[i] = fmaf(vv[u], (float)x[u][i], acc[i]);
        }
    }
    for (; j + 4 <= e; j += 4) {
        int cc[4]; float vv[4];
        #pragma unroll
        for (int u = 0; u < 4; ++u) cc[u] = __builtin_nontemporal_load(ecol + j + u);
        #pragma unroll
        for (int u = 0; u < 4; ++u) vv[u] = bfu2f(__builtin_nontemporal_load(eval + j + u));
        bf16x8 x[4];
        #pragma unroll
        for (int u = 0; u < 4; ++u)
            x[u] = *reinterpret_cast<const bf16x8*>(xb + (size_t)cc[u] * DDIM);
        __builtin_amdgcn_sched_barrier(0);
        #pragma unroll
        for (int u = 0; u < 4; ++u) {
            #pragma unroll
            for (int i = 0; i < 8; ++i) acc[i] = fmaf(vv[u], (float)x[u][i], acc[i]);
        }
    }
    for (; j < e; ++j) {
        int cc = __builtin_nontemporal_load(ecol + j);
        float vv = bfu2f(__builtin_nontemporal_load(eval + j));
        bf16x8 x = *reinterpret_cast<const bf16x8*>(xb + (size_t)cc * DDIM);
        #pragma unroll
        for (int i = 0; i < 8; ++i) acc[i] = fmaf(vv, (float)x[i], acc[i]);
    }
    size_t oi = (size_t)r * DDIM + lane * 8;
    bf16x8 y;
    #pragma unroll
    for (int i = 0; i < 8; ++i) y[i] = (__bf16)acc[i];
    *reinterpret_cast<bf16x8*>(Y + oi) = y;
}

// MFMA layer: 512 threads = 8 waves, 128 rows/block, 2 blocks/CU (64KB LDS, W only).
// A-streams prefetched one kk ahead; normbuf written only for sampled (flagged) rows.
__global__ __launch_bounds__(512, 4) void layer_kernel(
    const u16* __restrict__ ego, const u16* __restrict__ h1,
    const u16* __restrict__ h2, const u16* __restrict__ h3,
    const float* __restrict__ beta3,
    const u16* __restrict__ wtgc, const u16* __restrict__ wtbi,
    const float* __restrict__ bgc, const float* __restrict__ bbi,
    const unsigned char* __restrict__ flags,
    u16* __restrict__ ego_out, u16* __restrict__ normbuf) {
    __shared__ __align__(16) unsigned char smem[65536];
    const int WG = 0, WB = 32768;
    int tid = threadIdx.x;
    int base = blockIdx.x * LBM;
    float b0 = beta3[0], b1 = beta3[1], b2 = beta3[2];

    #pragma unroll
    for (int p = 0; p < 4; ++p) {
        int slot = tid + p * 512;            // 2048 16B slots
        int n = slot >> 4, ks = slot & 15;
        uint4 g  = *reinterpret_cast<const uint4*>(wtgc + n * DDIM + ks * 8);
        uint4 bq = *reinterpret_cast<const uint4*>(wtbi + n * DDIM + ks * 8);
        int addr = n * 256 + ((ks * 16) ^ ((n & 7) << 4));
        *reinterpret_cast<uint4*>(&smem[WG + addr]) = g;
        *reinterpret_cast<uint4*>(&smem[WB + addr]) = bq;
    }
    __syncthreads();

    int l = tid & 63, w = tid >> 6;
    int m = l & 15, g16 = l >> 4;
    int sw = (m & 7) << 4;
    int grow = base + w * 16 + m;
    bool ok = grow < NTOT;
    int grc = ok ? grow : 0;
    size_t aoff = (size_t)grc * DDIM + g16 * 8;

    bf16x8 c1 = *reinterpret_cast<const bf16x8*>(h1 + aoff);
    bf16x8 c2 = *reinterpret_cast<const bf16x8*>(h2 + aoff);
    bf16x8 c3 = *reinterpret_cast<const bf16x8*>(h3 + aoff);
    bf16x8 ce = *reinterpret_cast<const bf16x8*>(ego + aoff);

    f32x4 accg[8], accb[8];
    #pragma unroll
    for (int nt = 0; nt < 8; ++nt) {
        accg[nt] = (f32x4){0.f, 0.f, 0.f, 0.f};
        accb[nt] = (f32x4){0.f, 0.f, 0.f, 0.f};
    }
    #pragma unroll
    for (int kk = 0; kk < 4; ++kk) {
        bf16x8 p1, p2, p3, pe;
        if (kk < 3) {
            p1 = *reinterpret_cast<const bf16x8*>(h1 + aoff + (kk + 1) * 32);
            p2 = *reinterpret_cast<const bf16x8*>(h2 + aoff + (kk + 1) * 32);
            p3 = *reinterpret_cast<const bf16x8*>(h3 + aoff + (kk + 1) * 32);
            pe = *reinterpret_cast<const bf16x8*>(ego + aoff + (kk + 1) * 32);
            __builtin_amdgcn_sched_barrier(0);
        }
        bf16x8 as, ab;
        #pragma unroll
        for (int i = 0; i < 8; ++i) {
            float sf = ok ? (b0 * (float)c1[i] + b1 * (float)c2[i] + b2 * (float)c3[i]) : 0.f;
            as[i] = (__bf16)sf;
            ab[i] = (__bf16)(sf * (float)ce[i]);
        }
        int ka = (kk * 64 + g16 * 16) ^ sw;
        #pragma unroll
        for (int nt = 0; nt < 8; ++nt) {
            int na = (nt * 16 + m) * 256 + ka;
            bf16x8 bg = *reinterpret_cast<const bf16x8*>(&smem[WG + na]);
            accg[nt] = __builtin_amdgcn_mfma_f32_16x16x32_bf16(as, bg, accg[nt], 0, 0, 0);
            bf16x8 bb = *reinterpret_cast<const bf16x8*>(&smem[WB + na]);
            accb[nt] = __builtin_amdgcn_mfma_f32_16x16x32_bf16(ab, bb, accb[nt], 0, 0, 0);
        }
        if (kk < 3) { c1 = p1; c2 = p2; c3 = p3; ce = pe; }
    }
    // epilogue: bias + leaky + bilinear add; values stored back into accg
    float bgv[8], bbv[8];
    #pragma unroll
    for (int nt = 0; nt < 8; ++nt) { bgv[nt] = bgc[nt * 16 + m]; bbv[nt] = bbi[nt * 16 + m]; }
    float ss[4] = {0.f, 0.f, 0.f, 0.f};
    #pragma unroll
    for (int nt = 0; nt < 8; ++nt) {
        #pragma unroll
        for (int rr = 0; rr < 4; ++rr) {
            float se = accg[nt][rr] + bgv[nt];
            float be = accb[nt][rr] + bbv[nt];
            float v = (se > 0.f ? se : 0.2f * se) + be;
            accg[nt][rr] = v;
            ss[rr] += v * v;
            int row = base + w * 16 + g16 * 4 + rr;
            if (row < NTOT) ego_out[(size_t)row * DDIM + nt * 16 + m] = f2bfu(v);
        }
    }
    #pragma unroll
    for (int rr = 0; rr < 4; ++rr) {
        ss[rr] += __shfl_xor(ss[rr], 1, 64);
        ss[rr] += __shfl_xor(ss[rr], 2, 64);
        ss[rr] += __shfl_xor(ss[rr], 4, 64);
        ss[rr] += __shfl_xor(ss[rr], 8, 64);
        ss[rr] = 1.f / fmaxf(sqrtf(ss[rr]), 1e-12f);
    }
    // sparse normbuf write: only rows that will be gathered
    int frow = base + w * 16 + g16 * 4;
    #pragma unroll
    for (int rr = 0; rr < 4; ++rr) {
        int row = frow + rr;
        if (row < NTOT && flags[row]) {
            #pragma unroll
            for (int nt = 0; nt < 8; ++nt)
                normbuf[(size_t)row * DDIM + nt * 16 + m] = f2bfu(accg[nt][rr] * ss[rr]);
        }
    }
}

// slot 0: gather raw ego rows EXACTLY from the fp32 inputs; also mark sampled rows
__global__ void gather_ego_kernel(const float* __restrict__ feat, const float* __restrict__ user_emb,
                                  const float* __restrict__ item_emb1, const float* __restrict__ item_emb2,
                                  const int* __restrict__ users, const int* __restrict__ pos,
                                  const int* __restrict__ neg, float* __restrict__ out,
                                  unsigned char* __restrict__ flags) {
    int i = blockIdx.x * 256 + threadIdx.x;  // exactly 3*NB*128 threads
    int which = i / (NB * DDIM);
    int rem = i - which * (NB * DDIM);
    int b = rem >> 7, d = rem & 127;
    float v;
    int row;
    if (which == 0) {
        int u = users[b];
        row = u;
        v = (d < 64) ? user_emb[u*64 + d] : feat[u*64 + d - 64];
    } else {
        int m = (which == 1) ? pos[b] : neg[b];
        row = N_USERS + m;
        v = (d < 64) ? item_emb1[m*64 + d] : item_emb2[m*64 + d - 64];
    }
    if (d == 0) flags[row] = 1;
    out[(size_t)which * NB * 512 + (size_t)b * 512 + d] = v;
}

// slots 1..3: gather the 128-wide normalized slice from bf16 normbuf
__global__ void gather_slice_kernel(const u16* __restrict__ src, const int* __restrict__ users,
                                    const int* __restrict__ pos, const int* __restrict__ neg,
                                    float* __restrict__ out, int slot) {
    int i = blockIdx.x * 256 + threadIdx.x;  // exactly 3*NB*128 threads
    int which = i / (NB * DDIM);
    int rem = i - which * (NB * DDIM);
    int b = rem >> 7, c = rem & 127;
    int row;
    if (which == 0)      row = users[b];
    else if (which == 1) row = N_USERS + pos[b];
    else                 row = N_USERS + neg[b];
    unsigned int u = src[(size_t)row * DDIM + c];
    out[(size_t)which * NB * 512 + (size_t)b * 512 + slot * 128 + c] =
        __builtin_bit_cast(float, u << 16);
}

extern "C" void kernel_launch(void* const* d_in, const int* in_sizes, int n_in,
                              void* d_out, int out_size, void* d_ws, size_t ws_size,
                              hipStream_t stream) {
    (void)in_sizes; (void)n_in; (void)out_size; (void)ws_size;
    const int*   edge_row  = (const int*)  d_in[0];
    const int*   edge_col  = (const int*)  d_in[1];
    const float* edge_val  = (const float*)d_in[2];
    const float* feat      = (const float*)d_in[3];
    const float* user_emb  = (const float*)d_in[4];
    const float* item_emb1 = (const float*)d_in[5];
    const float* item_emb2 = (const float*)d_in[6];
    const float* alphas    = (const float*)d_in[7];
    const float* W_gc      = (const float*)d_in[8];
    const float* b_gc      = (const float*)d_in[9];
    const float* W_bi      = (const float*)d_in[10];
    const float* b_bi      = (const float*)d_in[11];
    const int*   users     = (const int*)  d_in[12];
    const int*   pos_items = (const int*)  d_in[13];
    const int*   neg_items = (const int*)  d_in[14];
    float* out = (float*)d_out;

    char* ws = (char*)d_ws;
    size_t off = 0;
    auto alloc = [&](size_t bytes) -> char* {
        char* p = ws + off;
        off = (off + bytes + 255) & ~(size_t)255;
        return p;
    };
    u16*   ego      = (u16*)  alloc((size_t)NTOT * DDIM * 2);   // 25.6 MB
    u16*   h1       = (u16*)  alloc((size_t)NTOT * DDIM * 2);   // 25.6 MB
    u16*   h2       = (u16*)  alloc((size_t)NTOT * DDIM * 2);   // 25.6 MB
    u16*   h3       = (u16*)  alloc((size_t)NTOT * DDIM * 2);   // 25.6 MB
    u16*   normbuf  = (u16*)  alloc((size_t)NTOT * DDIM * 2);   // 25.6 MB
    int*   rowptr   = (int*)  alloc((size_t)(NTOT + 1) * 4);
    int*   bbins    = (int*)  alloc((NBUK + 2) * 4);
    int*   bbase    = (int*)  alloc((NBUK + 2) * 4);
    int*   bcur     = (int*)  alloc((NBUK + 2) * 4);
    int*   ecol     = (int*)  alloc((size_t)NEDGE * 4);         // 6.4 MB
    u16*   eval     = (u16*)  alloc((size_t)NEDGE * 2);         // 3.2 MB
    unsigned char* flags = (unsigned char*)alloc(NTOT + 512);
    u16*   wtgc     = (u16*)  alloc((size_t)NLAY * DDIM * DDIM * 2);  // 96 KB
    u16*   wtbi     = (u16*)  alloc((size_t)NLAY * DDIM * DDIM * 2);  // 96 KB
    float* beta     = (float*)alloc(256);

    // tmp buffers for the 2-pass scatter alias h1 (dead until the first spmm fully rewrites it)
    int*  tmprow = (int*)h1;                                    // 6.4 MB
    int2* tmpcv  = (int2*)((char*)h1 + (size_t)NEDGE * 4);      // 12.8 MB (total 19.2 <= 25.6)

    build_ego_kernel<<<(NTOT * DDIM) / 256, 256, 0, stream>>>(feat, user_emb, item_emb1, item_emb2,
                                                              ego, bbins, flags);
    transpose_w_kernel<<<dim3(4, 4, 6), dim3(32, 8), 0, stream>>>(W_gc, W_bi, wtgc, wtbi);

    bhist_kernel<<<256, 256, 0, stream>>>(edge_row, bbins);
    beta_bscan_kernel<<<1, 64, 0, stream>>>(alphas, beta, bbins, bbase, bcur);
    bappend_kernel<<<(NEDGE + 2047) / 2048, 256, 0, stream>>>(edge_row, edge_col, edge_val,
                                                              bcur, tmprow, tmpcv);
    bfinal_kernel<<<NBUK, 1024, 0, stream>>>(bbase, tmprow, tmpcv, rowptr, ecol, eval);

    // slot 0 of the output: raw ego rows, exact fp32 (+ mark sampled rows)
    gather_ego_kernel<<<(3 * NB * DDIM) / 256, 256, 0, stream>>>(feat, user_emb, item_emb1, item_emb2,
                                                                 users, pos_items, neg_items, out, flags);

    int lgrid = (NTOT + LBM - 1) / LBM;   // 782
    for (int k = 0; k < NLAY; ++k) {
        spmm_kernel<<<NTOT / 16, 256, 0, stream>>>(rowptr, ecol, eval, ego, h1);
        spmm_kernel<<<NTOT / 16, 256, 0, stream>>>(rowptr, ecol, eval, h1, h2);
        spmm_kernel<<<NTOT / 16, 256, 0, stream>>>(rowptr, ecol, eval, h2, h3);
        layer_kernel<<<lgrid, 512, 0, stream>>>(ego, h1, h2, h3, beta + 3 * k,
                                                wtgc + (size_t)k * DDIM * DDIM, wtbi + (size_t)k * DDIM * DDIM,
                                                b_gc + (size_t)k * DDIM, b_bi + (size_t)k * DDIM,
                                                flags, ego, normbuf);
        gather_slice_kernel<<<(3 * NB * DDIM) / 256, 256, 0, stream>>>(normbuf, users, pos_items, neg_items, out, k + 1);
    }
}

// Round 14
// 794.333 us; speedup vs baseline: 1.0562x; 1.0562x over previous
//
#include <hip/hip_runtime.h>
#include <hip/hip_bf16.h>

typedef __hip_bfloat16 hbf16;
typedef unsigned short u16;
typedef __bf16 bf16x8 __attribute__((ext_vector_type(8)));
typedef float f32x4 __attribute__((ext_vector_type(4)));

#define N_USERS 80000
#define N_ITEMS 20000
#define NTOT    100000
#define NEDGE   1600000
#define DDIM    128
#define NLAY    3
#define KHOP    3
#define NB      4096
#define LBM     128    // rows per layer block
#define NBUK    98     // ceil(NTOT / 1024) row-buckets
#define BROWS   1024   // rows per bucket
#define BSH     10     // log2(BROWS)

__device__ inline u16 f2bfu(float f) { __bf16 h = (__bf16)f; return __builtin_bit_cast(u16, h); }

__global__ void build_ego_kernel(const float* __restrict__ feat, const float* __restrict__ user_emb,
                                 const float* __restrict__ item_emb1, const float* __restrict__ item_emb2,
                                 u16* __restrict__ ego, int* __restrict__ bbins,
                                 unsigned char* __restrict__ flags) {
    if (blockIdx.x == 0 && threadIdx.x < NBUK) bbins[threadIdx.x] = 0;
    int i = blockIdx.x * 256 + threadIdx.x;   // exactly NTOT*DDIM threads
    int n = i >> 7, d = i & 127;
    if (d == 0) flags[n] = 0;
    float v;
    if (n < N_USERS) {
        v = (d < 64) ? user_emb[n*64 + d] : feat[n*64 + d - 64];
    } else {
        int m = n - N_USERS;
        v = (d < 64) ? item_emb1[m*64 + d] : item_emb2[m*64 + d - 64];
    }
    ego[i] = f2bfu(v);
}

// transpose 6 128x128 fp32 matrices into bf16 (WT[n][k] = W[k][n])
__global__ void transpose_w_kernel(const float* __restrict__ Wgc, const float* __restrict__ Wbi,
                                   u16* __restrict__ WTgc, u16* __restrict__ WTbi) {
    __shared__ float t[32][33];
    int z = blockIdx.z;
    const float* W = (z < 3) ? (Wgc + (size_t)z * 16384) : (Wbi + (size_t)(z - 3) * 16384);
    u16* WT = (z < 3) ? (WTgc + (size_t)z * 16384) : (WTbi + (size_t)(z - 3) * 16384);
    int r0 = blockIdx.y * 32, c0 = blockIdx.x * 32;
    for (int i = threadIdx.y; i < 32; i += 8)
        t[i][threadIdx.x] = W[(size_t)(r0 + i) * 128 + c0 + threadIdx.x];
    __syncthreads();
    for (int i = threadIdx.y; i < 32; i += 8)
        WT[(size_t)(c0 + i) * 128 + r0 + threadIdx.x] = f2bfu(t[threadIdx.x][i]);
}

// Pass A: bucket histogram (98 bins, LDS-aggregated)
__global__ __launch_bounds__(256) void bhist_kernel(const int* __restrict__ er,
                                                    int* __restrict__ bbins) {
    __shared__ int l[NBUK];
    int tid = threadIdx.x;
    if (tid < NBUK) l[tid] = 0;
    __syncthreads();
    for (int i = blockIdx.x * 256 + tid; i < NEDGE; i += gridDim.x * 256)
        atomicAdd(&l[er[i] >> BSH], 1);
    __syncthreads();
    if (tid < NBUK && l[tid]) atomicAdd(&bbins[tid], l[tid]);
}

// Pass B: beta softmax + bucket exclusive scan (merged tiny scalar kernels)
__global__ void beta_bscan_kernel(const float* __restrict__ alphas, float* __restrict__ beta,
                                  const int* __restrict__ bbins, int* __restrict__ bbase,
                                  int* __restrict__ bcur) {
    if (threadIdx.x == 0 && blockIdx.x == 0) {
        for (int k = 0; k < NLAY; ++k) {
            float a[KHOP];
            float m = -1e30f;
            for (int i = 0; i < KHOP; ++i) { a[i] = alphas[k*KHOP+i]; m = fmaxf(m, a[i]); }
            float s = 0.f;
            for (int i = 0; i < KHOP; ++i) { a[i] = expf(a[i] - m); s += a[i]; }
            for (int i = 0; i < KHOP; ++i) beta[k*KHOP+i] = a[i] / s;
        }
        int acc = 0;
        for (int b = 0; b < NBUK; ++b) { int t = bbins[b]; bbase[b] = acc; bcur[b] = acc; acc += t; }
        bbase[NBUK] = acc;
    }
}

// Pass C: append edges into row-buckets (per-block LDS aggregation -> contiguous runs)
__global__ __launch_bounds__(256) void bappend_kernel(
    const int* __restrict__ er, const int* __restrict__ ec, const float* __restrict__ ev,
    int* __restrict__ bcur, int* __restrict__ tmprow, int2* __restrict__ tmpcv) {
    __shared__ int lcnt[NBUK], lbase[NBUK], lrank[NBUK];
    int tid = threadIdx.x;
    for (int b = tid; b < NBUK; b += 256) { lcnt[b] = 0; lrank[b] = 0; }
    __syncthreads();
    int base = blockIdx.x * 2048;
    int r[8], c[8], vb[8], bk[8];
    bool ok[8];
    #pragma unroll
    for (int k = 0; k < 8; ++k) {
        int i = base + k * 256 + tid;
        ok[k] = i < NEDGE;
        bk[k] = 0;
        if (ok[k]) {
            r[k] = er[i]; c[k] = ec[i]; vb[k] = __float_as_int(ev[i]);
            bk[k] = r[k] >> BSH;
            atomicAdd(&lcnt[bk[k]], 1);
        }
    }
    __syncthreads();
    for (int b = tid; b < NBUK; b += 256)
        lbase[b] = lcnt[b] ? atomicAdd(&bcur[b], lcnt[b]) : 0;
    __syncthreads();
    #pragma unroll
    for (int k = 0; k < 8; ++k) {
        if (ok[k]) {
            int rank = atomicAdd(&lrank[bk[k]], 1);
            int pos = lbase[bk[k]] + rank;
            tmprow[pos] = r[k];
            tmpcv[pos] = make_int2(c[k], vb[k]);
        }
    }
}

// Pass D: one block per bucket (98 blocks). LDS row-histogram + 1024-wide scan ->
// rowptr (coalesced), then LDS running counters place edges (8B packed records).
__global__ __launch_bounds__(1024) void bfinal_kernel(
    const int* __restrict__ bbase, const int* __restrict__ tmprow,
    const int2* __restrict__ tmpcv, int* __restrict__ rowptr, int2* __restrict__ edges) {
    __shared__ int lhist[BROWS];
    __shared__ int s2[1024];
    int b = blockIdx.x, tid = threadIdx.x;
    int s = bbase[b], e = bbase[b + 1];
    int rbase = b << BSH;
    int nrows = min(NTOT - rbase, BROWS);
    lhist[tid] = 0;
    __syncthreads();
    for (int i = s + tid; i < e; i += 1024)
        atomicAdd(&lhist[tmprow[i] - rbase], 1);
    __syncthreads();
    int a = lhist[tid];
    s2[tid] = a;
    __syncthreads();
    for (int off = 1; off < 1024; off <<= 1) {
        int t = (tid >= off) ? s2[tid - off] : 0;
        __syncthreads();
        s2[tid] += t;
        __syncthreads();
    }
    int excl = s2[tid] - a;
    if (tid < nrows) rowptr[rbase + tid] = s + excl;
    if (b == NBUK - 1 && tid == 0) rowptr[NTOT] = NEDGE;
    lhist[tid] = excl;
    __syncthreads();
    for (int i = s + tid; i < e; i += 1024) {
        int lr = tmprow[i] - rbase;
        int p = atomicAdd(&lhist[lr], 1);
        edges[s + p] = tmpcv[i];
    }
}

__device__ inline void ld_edge_nt(const int2* __restrict__ p, int& c, float& v) {
    unsigned long long rec =
        __builtin_nontemporal_load(reinterpret_cast<const unsigned long long*>(p));
    c = (int)(unsigned)(rec & 0xffffffffull);
    v = __int_as_float((int)(unsigned)(rec >> 32));
}

// 16 lanes per row, 16 rows per 256-thread block; each lane owns 8 columns (16B loads).
// Packed 8B edge records, single nontemporal load (r12 configuration — measured floor:
// 65.5-66us / 194MB FETCH, invariant to ILP & occupancy across r10-r13 interventions).
__global__ __launch_bounds__(256) void spmm_kernel(
    const int* __restrict__ rowptr, const int2* __restrict__ edges,
    const u16* __restrict__ X, u16* __restrict__ Y) {
    int tid = threadIdx.x;
    int r = blockIdx.x * 16 + (tid >> 4);
    int lane = tid & 15;
    int s = rowptr[r], e = rowptr[r + 1];
    float acc[8];
    #pragma unroll
    for (int i = 0; i < 8; ++i) acc[i] = 0.f;
    const u16* xb = X + lane * 8;
    int j = s;
    for (; j + 8 <= e; j += 8) {
        int cc[8]; float vv[8];
        #pragma unroll
        for (int u = 0; u < 8; ++u) ld_edge_nt(edges + j + u, cc[u], vv[u]);
        bf16x8 x[8];
        #pragma unroll
        for (int u = 0; u < 8; ++u)
            x[u] = *reinterpret_cast<const bf16x8*>(xb + (size_t)cc[u] * DDIM);
        __builtin_amdgcn_sched_barrier(0);
        #pragma unroll
        for (int u = 0; u < 8; ++u) {
            #pragma unroll
            for (int i = 0; i < 8; ++i) acc[i] = fmaf(vv[u], (float)x[u][i], acc[i]);
        }
    }
    for (; j + 4 <= e; j += 4) {
        int cc[4]; float vv[4];
        #pragma unroll
        for (int u = 0; u < 4; ++u) ld_edge_nt(edges + j + u, cc[u], vv[u]);
        bf16x8 x[4];
        #pragma unroll
        for (int u = 0; u < 4; ++u)
            x[u] = *reinterpret_cast<const bf16x8*>(xb + (size_t)cc[u] * DDIM);
        __builtin_amdgcn_sched_barrier(0);
        #pragma unroll
        for (int u = 0; u < 4; ++u) {
            #pragma unroll
            for (int i = 0; i < 8; ++i) acc[i] = fmaf(vv[u], (float)x[u][i], acc[i]);
        }
    }
    for (; j < e; ++j) {
        int cc; float vv;
        ld_edge_nt(edges + j, cc, vv);
        bf16x8 x = *reinterpret_cast<const bf16x8*>(xb + (size_t)cc * DDIM);
        #pragma unroll
        for (int i = 0; i < 8; ++i) acc[i] = fmaf(vv, (float)x[i], acc[i]);
    }
    size_t oi = (size_t)r * DDIM + lane * 8;
    bf16x8 y;
    #pragma unroll
    for (int i = 0; i < 8; ++i) y[i] = (__bf16)acc[i];
    *reinterpret_cast<bf16x8*>(Y + oi) = y;
}

// MFMA layer: 512 threads = 8 waves, 128 rows/block, 2 blocks/CU (64KB LDS, W only).
// A-streams prefetched one kk ahead; normbuf written only for sampled (flagged) rows.
__global__ __launch_bounds__(512, 4) void layer_kernel(
    const u16* __restrict__ ego, const u16* __restrict__ h1,
    const u16* __restrict__ h2, const u16* __restrict__ h3,
    const float* __restrict__ beta3,
    const u16* __restrict__ wtgc, const u16* __restrict__ wtbi,
    const float* __restrict__ bgc, const float* __restrict__ bbi,
    const unsigned char* __restrict__ flags,
    u16* __restrict__ ego_out, u16* __restrict__ normbuf) {
    __shared__ __align__(16) unsigned char smem[65536];
    const int WG = 0, WB = 32768;
    int tid = threadIdx.x;
    int base = blockIdx.x * LBM;
    float b0 = beta3[0], b1 = beta3[1], b2 = beta3[2];

    #pragma unroll
    for (int p = 0; p < 4; ++p) {
        int slot = tid + p * 512;            // 2048 16B slots
        int n = slot >> 4, ks = slot & 15;
        uint4 g  = *reinterpret_cast<const uint4*>(wtgc + n * DDIM + ks * 8);
        uint4 bq = *reinterpret_cast<const uint4*>(wtbi + n * DDIM + ks * 8);
        int addr = n * 256 + ((ks * 16) ^ ((n & 7) << 4));
        *reinterpret_cast<uint4*>(&smem[WG + addr]) = g;
        *reinterpret_cast<uint4*>(&smem[WB + addr]) = bq;
    }
    __syncthreads();

    int l = tid & 63, w = tid >> 6;
    int m = l & 15, g16 = l >> 4;
    int sw = (m & 7) << 4;
    int grow = base + w * 16 + m;
    bool ok = grow < NTOT;
    int grc = ok ? grow : 0;
    size_t aoff = (size_t)grc * DDIM + g16 * 8;

    bf16x8 c1 = *reinterpret_cast<const bf16x8*>(h1 + aoff);
    bf16x8 c2 = *reinterpret_cast<const bf16x8*>(h2 + aoff);
    bf16x8 c3 = *reinterpret_cast<const bf16x8*>(h3 + aoff);
    bf16x8 ce = *reinterpret_cast<const bf16x8*>(ego + aoff);

    f32x4 accg[8], accb[8];
    #pragma unroll
    for (int nt = 0; nt < 8; ++nt) {
        accg[nt] = (f32x4){0.f, 0.f, 0.f, 0.f};
        accb[nt] = (f32x4){0.f, 0.f, 0.f, 0.f};
    }
    #pragma unroll
    for (int kk = 0; kk < 4; ++kk) {
        bf16x8 p1, p2, p3, pe;
        if (kk < 3) {
            p1 = *reinterpret_cast<const bf16x8*>(h1 + aoff + (kk + 1) * 32);
            p2 = *reinterpret_cast<const bf16x8*>(h2 + aoff + (kk + 1) * 32);
            p3 = *reinterpret_cast<const bf16x8*>(h3 + aoff + (kk + 1) * 32);
            pe = *reinterpret_cast<const bf16x8*>(ego + aoff + (kk + 1) * 32);
            __builtin_amdgcn_sched_barrier(0);
        }
        bf16x8 as, ab;
        #pragma unroll
        for (int i = 0; i < 8; ++i) {
            float sf = ok ? (b0 * (float)c1[i] + b1 * (float)c2[i] + b2 * (float)c3[i]) : 0.f;
            as[i] = (__bf16)sf;
            ab[i] = (__bf16)(sf * (float)ce[i]);
        }
        int ka = (kk * 64 + g16 * 16) ^ sw;
        #pragma unroll
        for (int nt = 0; nt < 8; ++nt) {
            int na = (nt * 16 + m) * 256 + ka;
            bf16x8 bg = *reinterpret_cast<const bf16x8*>(&smem[WG + na]);
            accg[nt] = __builtin_amdgcn_mfma_f32_16x16x32_bf16(as, bg, accg[nt], 0, 0, 0);
            bf16x8 bb = *reinterpret_cast<const bf16x8*>(&smem[WB + na]);
            accb[nt] = __builtin_amdgcn_mfma_f32_16x16x32_bf16(ab, bb, accb[nt], 0, 0, 0);
        }
        if (kk < 3) { c1 = p1; c2 = p2; c3 = p3; ce = pe; }
    }
    // epilogue: bias + leaky + bilinear add; values stored back into accg
    float bgv[8], bbv[8];
    #pragma unroll
    for (int nt = 0; nt < 8; ++nt) { bgv[nt] = bgc[nt * 16 + m]; bbv[nt] = bbi[nt * 16 + m]; }
    float ss[4] = {0.f, 0.f, 0.f, 0.f};
    #pragma unroll
    for (int nt = 0; nt < 8; ++nt) {
        #pragma unroll
        for (int rr = 0; rr < 4; ++rr) {
            float se = accg[nt][rr] + bgv[nt];
            float be = accb[nt][rr] + bbv[nt];
            float v = (se > 0.f ? se : 0.2f * se) + be;
            accg[nt][rr] = v;
            ss[rr] += v * v;
            int row = base + w * 16 + g16 * 4 + rr;
            if (row < NTOT) ego_out[(size_t)row * DDIM + nt * 16 + m] = f2bfu(v);
        }
    }
    #pragma unroll
    for (int rr = 0; rr < 4; ++rr) {
        ss[rr] += __shfl_xor(ss[rr], 1, 64);
        ss[rr] += __shfl_xor(ss[rr], 2, 64);
        ss[rr] += __shfl_xor(ss[rr], 4, 64);
        ss[rr] += __shfl_xor(ss[rr], 8, 64);
        ss[rr] = 1.f / fmaxf(sqrtf(ss[rr]), 1e-12f);
    }
    // sparse normbuf write: only rows that will be gathered
    int frow = base + w * 16 + g16 * 4;
    #pragma unroll
    for (int rr = 0; rr < 4; ++rr) {
        int row = frow + rr;
        if (row < NTOT && flags[row]) {
            #pragma unroll
            for (int nt = 0; nt < 8; ++nt)
                normbuf[(size_t)row * DDIM + nt * 16 + m] = f2bfu(accg[nt][rr] * ss[rr]);
        }
    }
}

// slot 0: gather raw ego rows EXACTLY from the fp32 inputs; also mark sampled rows
__global__ void gather_ego_kernel(const float* __restrict__ feat, const float* __restrict__ user_emb,
                                  const float* __restrict__ item_emb1, const float* __restrict__ item_emb2,
                                  const int* __restrict__ users, const int* __restrict__ pos,
                                  const int* __restrict__ neg, float* __restrict__ out,
                                  unsigned char* __restrict__ flags) {
    int i = blockIdx.x * 256 + threadIdx.x;  // exactly 3*NB*128 threads
    int which = i / (NB * DDIM);
    int rem = i - which * (NB * DDIM);
    int b = rem >> 7, d = rem & 127;
    float v;
    int row;
    if (which == 0) {
        int u = users[b];
        row = u;
        v = (d < 64) ? user_emb[u*64 + d] : feat[u*64 + d - 64];
    } else {
        int m = (which == 1) ? pos[b] : neg[b];
        row = N_USERS + m;
        v = (d < 64) ? item_emb1[m*64 + d] : item_emb2[m*64 + d - 64];
    }
    if (d == 0) flags[row] = 1;
    out[(size_t)which * NB * 512 + (size_t)b * 512 + d] = v;
}

// slots 1..3: gather the 128-wide normalized slice from bf16 normbuf
__global__ void gather_slice_kernel(const u16* __restrict__ src, const int* __restrict__ users,
                                    const int* __restrict__ pos, const int* __restrict__ neg,
                                    float* __restrict__ out, int slot) {
    int i = blockIdx.x * 256 + threadIdx.x;  // exactly 3*NB*128 threads
    int which = i / (NB * DDIM);
    int rem = i - which * (NB * DDIM);
    int b = rem >> 7, c = rem & 127;
    int row;
    if (which == 0)      row = users[b];
    else if (which == 1) row = N_USERS + pos[b];
    else                 row = N_USERS + neg[b];
    unsigned int u = src[(size_t)row * DDIM + c];
    out[(size_t)which * NB * 512 + (size_t)b * 512 + slot * 128 + c] =
        __builtin_bit_cast(float, u << 16);
}

extern "C" void kernel_launch(void* const* d_in, const int* in_sizes, int n_in,
                              void* d_out, int out_size, void* d_ws, size_t ws_size,
                              hipStream_t stream) {
    (void)in_sizes; (void)n_in; (void)out_size; (void)ws_size;
    const int*   edge_row  = (const int*)  d_in[0];
    const int*   edge_col  = (const int*)  d_in[1];
    const float* edge_val  = (const float*)d_in[2];
    const float* feat      = (const float*)d_in[3];
    const float* user_emb  = (const float*)d_in[4];
    const float* item_emb1 = (const float*)d_in[5];
    const float* item_emb2 = (const float*)d_in[6];
    const float* alphas    = (const float*)d_in[7];
    const float* W_gc      = (const float*)d_in[8];
    const float* b_gc      = (const float*)d_in[9];
    const float* W_bi      = (const float*)d_in[10];
    const float* b_bi      = (const float*)d_in[11];
    const int*   users     = (const int*)  d_in[12];
    const int*   pos_items = (const int*)  d_in[13];
    const int*   neg_items = (const int*)  d_in[14];
    float* out = (float*)d_out;

    char* ws = (char*)d_ws;
    size_t off = 0;
    auto alloc = [&](size_t bytes) -> char* {
        char* p = ws + off;
        off = (off + bytes + 255) & ~(size_t)255;
        return p;
    };
    u16*   ego      = (u16*)  alloc((size_t)NTOT * DDIM * 2);   // 25.6 MB
    u16*   h1       = (u16*)  alloc((size_t)NTOT * DDIM * 2);   // 25.6 MB
    u16*   h2       = (u16*)  alloc((size_t)NTOT * DDIM * 2);   // 25.6 MB
    u16*   h3       = (u16*)  alloc((size_t)NTOT * DDIM * 2);   // 25.6 MB
    u16*   normbuf  = (u16*)  alloc((size_t)NTOT * DDIM * 2);   // 25.6 MB
    int*   rowptr   = (int*)  alloc((size_t)(NTOT + 1) * 4);
    int*   bbins    = (int*)  alloc((NBUK + 2) * 4);
    int*   bbase    = (int*)  alloc((NBUK + 2) * 4);
    int*   bcur     = (int*)  alloc((NBUK + 2) * 4);
    int2*  edges    = (int2*) alloc((size_t)NEDGE * 8);         // 12.8 MB
    unsigned char* flags = (unsigned char*)alloc(NTOT + 512);
    u16*   wtgc     = (u16*)  alloc((size_t)NLAY * DDIM * DDIM * 2);  // 96 KB
    u16*   wtbi     = (u16*)  alloc((size_t)NLAY * DDIM * DDIM * 2);  // 96 KB
    float* beta     = (float*)alloc(256);

    // tmp buffers for the 2-pass scatter alias h1 (dead until the first spmm fully rewrites it)
    int*  tmprow = (int*)h1;                                    // 6.4 MB
    int2* tmpcv  = (int2*)((char*)h1 + (size_t)NEDGE * 4);      // 12.8 MB (total 19.2 <= 25.6)

    build_ego_kernel<<<(NTOT * DDIM) / 256, 256, 0, stream>>>(feat, user_emb, item_emb1, item_emb2,
                                                              ego, bbins, flags);
    transpose_w_kernel<<<dim3(4, 4, 6), dim3(32, 8), 0, stream>>>(W_gc, W_bi, wtgc, wtbi);

    bhist_kernel<<<256, 256, 0, stream>>>(edge_row, bbins);
    beta_bscan_kernel<<<1, 64, 0, stream>>>(alphas, beta, bbins, bbase, bcur);
    bappend_kernel<<<(NEDGE + 2047) / 2048, 256, 0, stream>>>(edge_row, edge_col, edge_val,
                                                              bcur, tmprow, tmpcv);
    bfinal_kernel<<<NBUK, 1024, 0, stream>>>(bbase, tmprow, tmpcv, rowptr, edges);

    // slot 0 of the output: raw ego rows, exact fp32 (+ mark sampled rows)
    gather_ego_kernel<<<(3 * NB * DDIM) / 256, 256, 0, stream>>>(feat, user_emb, item_emb1, item_emb2,
                                                                 users, pos_items, neg_items, out, flags);

    int lgrid = (NTOT + LBM - 1) / LBM;   // 782
    for (int k = 0; k < NLAY; ++k) {
        spmm_kernel<<<NTOT / 16, 256, 0, stream>>>(rowptr, edges, ego, h1);
        spmm_kernel<<<NTOT / 16, 256, 0, stream>>>(rowptr, edges, h1, h2);
        spmm_kernel<<<NTOT / 16, 256, 0, stream>>>(rowptr, edges, h2, h3);
        layer_kernel<<<lgrid, 512, 0, stream>>>(ego, h1, h2, h3, beta + 3 * k,
                                                wtgc + (size_t)k * DDIM * DDIM, wtbi + (size_t)k * DDIM * DDIM,
                                                b_gc + (size_t)k * DDIM, b_bi + (size_t)k * DDIM,
                                                flags, ego, normbuf);
        gather_slice_kernel<<<(3 * NB * DDIM) / 256, 256, 0, stream>>>(normbuf, users, pos_items, neg_items, out, k + 1);
    }
}